// Round 1
// baseline (299.439 us; speedup 1.0000x reference)
//
#include <hip/hip_runtime.h>

#define PP 8732
#define NB 20
#define NC 21
#define BTH 256
#define NW (BTH/64)

__device__ __forceinline__ float sl1(float d){
  float a = fabsf(d);
  return a < 1.0f ? 0.5f*a*a : a - 0.5f;
}

extern "C" __global__ void __launch_bounds__(BTH)
mb_row(const float* __restrict__ loc_data,
       const float* __restrict__ conf_data,
       const float* __restrict__ priors,
       const float* __restrict__ targets,
       float* __restrict__ ws)
{
  const int b    = blockIdx.x;
  const int tid  = threadIdx.x;
  const int lane = tid & 63;
  const int wid  = tid >> 6;

  __shared__ float s_tr[NB][4];
  __shared__ float s_lab[NB];
  __shared__ float s_val[PP];          // pass1: best_truth_overlap; pass2+: rank (loss_c)
  __shared__ unsigned char s_idx[PP];  // best truth index per prior
  __shared__ int s_bp[NB];             // best prior index per truth
  __shared__ unsigned long long s_scr64[NW];
  __shared__ float s_scrf[2*NW];
  __shared__ int s_scri[NW];
  __shared__ float s_resf[3];  // 0: loss_l, 1: pos ce sum, 2: special ce at (0,0)
  __shared__ int s_resi[2];    // 0: num_pos, 1: special valid

  // load truths/labels
  if (tid < NB*5){
    int n = tid/5, k = tid - n*5;
    float v = targets[((long)b*NB + n)*5 + k];
    if (k < 4) s_tr[n][k] = v; else s_lab[n] = v;
  }
  if (tid == 0){ s_resi[1] = 0; s_resf[2] = 0.f; }
  __syncthreads();

  // ---- pass 1: IoUs; per-prior best truth (first-max), per-truth best prior (first-max) ----
  unsigned long long bk[NB];
  #pragma unroll
  for (int n=0;n<NB;n++) bk[n]=0ULL;

  for (int p = tid; p < PP; p += BTH){
    float4 pr = reinterpret_cast<const float4*>(priors)[p];
    float bx1 = pr.x - pr.z*0.5f, by1 = pr.y - pr.w*0.5f;
    float bx2 = pr.x + pr.z*0.5f, by2 = pr.y + pr.w*0.5f;
    float area_b = (bx2-bx1)*(by2-by1);
    float bestov = -1.0f; int bestn = 0;
    #pragma unroll
    for (int n=0;n<NB;n++){
      float tx1=s_tr[n][0], ty1=s_tr[n][1], tx2=s_tr[n][2], ty2=s_tr[n][3];
      float lx=fmaxf(tx1,bx1), ly=fmaxf(ty1,by1);
      float rx=fminf(tx2,bx2), ry=fminf(ty2,by2);
      float w=fmaxf(rx-lx,0.f), h=fmaxf(ry-ly,0.f);
      float inter=w*h;
      float area_a=(tx2-tx1)*(ty2-ty1);
      float iou = inter/(area_a+area_b-inter);
      if (iou > bestov){ bestov=iou; bestn=n; }          // strict > = first-max over n
      unsigned long long key = ((unsigned long long)__float_as_uint(iou)<<32)
                             | (unsigned long long)(0xFFFFFFFFu - (unsigned)p);
      if (key > bk[n]) bk[n] = key;                      // max iou, tie -> min p
    }
    s_val[p]=bestov; s_idx[p]=(unsigned char)bestn;
  }
  __syncthreads();

  for (int n=0;n<NB;n++){
    unsigned long long k = bk[n];
    #pragma unroll
    for (int o=32;o;o>>=1){ unsigned long long w=__shfl_down(k,o,64); if (w>k) k=w; }
    if (lane==0) s_scr64[wid]=k;
    __syncthreads();
    if (tid==0){
      unsigned long long m = s_scr64[0];
      for (int w=1;w<NW;w++) if (s_scr64[w]>m) m=s_scr64[w];
      s_bp[n] = (int)(0xFFFFFFFFu - (unsigned)(m & 0xFFFFFFFFULL));
    }
    __syncthreads();
  }

  if (tid==0){
    // scatter: overlap=2.0; chosen = max n per prior (ascending overwrite)
    for (int n=0;n<NB;n++){ int p=s_bp[n]; s_val[p]=2.0f; s_idx[p]=(unsigned char)n; }
  }
  __syncthreads();

  // ---- pass 2: conf_t, encode + smooth_l1, logsumexp, rank values ----
  float loss_l=0.f, posce=0.f; int npos=0;
  for (int p = tid; p < PP; p += BTH){
    float ov = s_val[p];
    int idx = s_idx[p];
    int ct = (ov < 0.5f) ? 0 : ((int)s_lab[idx] + 1);
    const float* cp = conf_data + ((long)b*PP + p)*NC;
    float v[NC];
    #pragma unroll
    for (int c=0;c<NC;c++) v[c]=cp[c];
    float m=v[0];
    #pragma unroll
    for (int c=1;c<NC;c++) m=fmaxf(m,v[c]);
    float s=0.f;
    #pragma unroll
    for (int c=0;c<NC;c++) s += expf(v[c]-m);
    float lse = logf(s)+m;
    float rank;
    if (ct > 0){
      float vct = v[0];
      #pragma unroll
      for (int c=1;c<NC;c++) if (ct==c) vct=v[c];
      posce += lse - vct;
      npos++;
      float tx1=s_tr[idx][0], ty1=s_tr[idx][1], tx2=s_tr[idx][2], ty2=s_tr[idx][3];
      float4 pr = reinterpret_cast<const float4*>(priors)[p];
      float g0 = ((tx1+tx2)*0.5f - pr.x) / (0.1f*pr.z);
      float g1 = ((ty1+ty2)*0.5f - pr.y) / (0.1f*pr.w);
      float g2 = logf((tx2-tx1)/pr.z) / 0.2f;
      float g3 = logf((ty2-ty1)/pr.w) / 0.2f;
      float4 ld = reinterpret_cast<const float4*>(loc_data)[(long)b*PP + p];
      loss_l += sl1(ld.x-g0)+sl1(ld.y-g1)+sl1(ld.z-g2)+sl1(ld.w-g3);
      rank = 0.f;
    } else {
      // clamped class: 0, except flat index 0 (b==0,p==0) which is forced to 1
      float cl = (b==0 && p==0) ? v[1] : v[0];
      rank = lse - cl;
      if (b==0 && p==0){ s_resf[2] = lse - v[0]; s_resi[1] = 1; }  // true ce if picked as neg
    }
    s_val[p] = rank;
  }
  #pragma unroll
  for (int o=32;o;o>>=1){
    loss_l += __shfl_down(loss_l,o,64);
    posce  += __shfl_down(posce,o,64);
    npos   += __shfl_down(npos,o,64);
  }
  __syncthreads();
  if (lane==0){ s_scrf[wid]=loss_l; s_scrf[NW+wid]=posce; s_scri[wid]=npos; }
  __syncthreads();
  if (tid==0){
    float a=0.f,c2=0.f; int ni=0;
    for (int w=0;w<NW;w++){ a+=s_scrf[w]; c2+=s_scrf[NW+w]; ni+=s_scri[w]; }
    s_resf[0]=a; s_resf[1]=c2; s_resi[0]=ni;
  }
  __syncthreads();
  const int num_pos = s_resi[0];
  int k = num_pos*3; if (k > PP-1) k = PP-1;

  // ---- pass 3: k-th largest rank via binary search on float bits (all ranks >= 0) ----
  unsigned lo=0u, hi=0x7f800000u;
  while (lo < hi){
    unsigned mid = lo + ((hi - lo + 1u) >> 1);
    int c=0;
    for (int p=tid;p<PP;p+=BTH) c += (__float_as_uint(s_val[p]) >= mid) ? 1 : 0;
    #pragma unroll
    for (int o=32;o;o>>=1) c += __shfl_down(c,o,64);
    __syncthreads();
    if (lane==0) s_scri[wid]=c;
    __syncthreads();
    int tot=0;
    for (int w=0;w<NW;w++) tot+=s_scri[w];
    if (tot >= k) lo = mid; else hi = mid - 1u;
  }
  const unsigned vstar = lo;

  int cg=0; float sg=0.f;
  for (int p=tid;p<PP;p+=BTH){
    float rv = s_val[p];
    if (__float_as_uint(rv) > vstar){ cg++; sg += rv; }
  }
  #pragma unroll
  for (int o=32;o;o>>=1){ cg += __shfl_down(cg,o,64); sg += __shfl_down(sg,o,64); }
  __syncthreads();
  if (lane==0){ s_scri[wid]=cg; s_scrf[wid]=sg; }
  __syncthreads();
  if (tid==0){
    int cG=0; float sumG=0.f;
    for (int w=0;w<NW;w++){ cG+=s_scri[w]; sumG+=s_scrf[w]; }
    int tie = k - cG;   // 1 <= tie <= multiplicity of vstar (stable ties: lowest indices first)
    float negsum = sumG + (float)tie * __uint_as_float(vstar);
    // correction for flat index 0: its ranking value used class 1, but its ce uses class 0.
    // index 0 is always first among equal-valued ties, so selected iff bits >= vstar.
    if (b==0 && s_resi[1]){
      if (__float_as_uint(s_val[0]) >= vstar) negsum += s_resf[2] - s_val[0];
    }
    ws[b*3+0] = s_resf[0];
    ws[b*3+1] = s_resf[1] + negsum;
    ws[b*3+2] = (float)num_pos;
  }
}

extern "C" __global__ void mb_final(const float* __restrict__ ws, float* __restrict__ out, int B){
  if (threadIdx.x==0 && blockIdx.x==0){
    float ll=0.f, lc=0.f, np=0.f;
    for (int i=0;i<B;i++){ ll+=ws[i*3]; lc+=ws[i*3+1]; np+=ws[i*3+2]; }
    out[0]=ll/np; out[1]=lc/np;
  }
}

extern "C" void kernel_launch(void* const* d_in, const int* in_sizes, int n_in,
                              void* d_out, int out_size, void* d_ws, size_t ws_size,
                              hipStream_t stream) {
  const float* loc     = (const float*)d_in[0];
  const float* conf    = (const float*)d_in[1];
  const float* priors  = (const float*)d_in[2];
  const float* targets = (const float*)d_in[3];
  float* ws  = (float*)d_ws;
  float* out = (float*)d_out;
  int B = in_sizes[0] / (PP*4);
  hipLaunchKernelGGL(mb_row, dim3(B), dim3(BTH), 0, stream, loc, conf, priors, targets, ws);
  hipLaunchKernelGGL(mb_final, dim3(1), dim3(64), 0, stream, ws, out, B);
}

// Round 2
// 274.160 us; speedup vs baseline: 1.0922x; 1.0922x over previous
//
#include <hip/hip_runtime.h>

#define PP 8732
#define NB 20
#define NC 21
#define BTH 256
#define NW (BTH/64)
#define SA 8
#define SC 16
#define CHA ((PP + SA - 1)/SA)   // 1092 priors per match block
#define CHC ((PP + SC - 1)/SC)   // 546 priors per rank block

// ws layout (bytes):
//   0     : keys  u64 [B][NB]   per-truth best-prior packed keys (20480 B)
//   20480 : facc  float[8]      0=loss_l 1=posce 2=special_ce 3=negsum_total
//   20512 : iacc  int[8]        0=special_flag (flat index 0 was negative)
//   20544 : npos  int[B]
//   32768 : rank  float[B][PP]  pass A: best_truth_overlap; pass C: loss_c rank value
//   32768+B*PP*4 : idx uchar[B][PP]
#define OFF_FACC 20480
#define OFF_IACC 20512
#define OFF_NPOS 20544
#define OFF_RANK 32768

__device__ __forceinline__ float sl1(float d){
  float a = fabsf(d);
  return a < 1.0f ? 0.5f*a*a : a - 0.5f;
}

// ---- A: IoU matching. grid (B, SA) ----
extern "C" __global__ void __launch_bounds__(BTH)
mb_match(const float* __restrict__ priors, const float* __restrict__ targets,
         float* __restrict__ rank, unsigned char* __restrict__ idxa,
         unsigned long long* __restrict__ keys)
{
  const int b = blockIdx.x, tid = threadIdx.x, lane = tid & 63;
  __shared__ float s_tr[NB][4];
  if (tid < NB*5){
    int n = tid/5, k2 = tid - n*5;
    float v = targets[((long)b*NB + n)*5 + k2];
    if (k2 < 4) s_tr[n][k2] = v;
  }
  __syncthreads();

  unsigned long long bk[NB];
  #pragma unroll
  for (int n=0;n<NB;n++) bk[n]=0ULL;

  const int base = blockIdx.y*CHA;
  const int end  = (base + CHA < PP) ? base + CHA : PP;
  for (int p = base + tid; p < end; p += BTH){
    float4 pr = reinterpret_cast<const float4*>(priors)[p];
    float bx1 = pr.x - pr.z*0.5f, by1 = pr.y - pr.w*0.5f;
    float bx2 = pr.x + pr.z*0.5f, by2 = pr.y + pr.w*0.5f;
    float area_b = (bx2-bx1)*(by2-by1);
    float bestov = -1.0f; int bestn = 0;
    #pragma unroll
    for (int n=0;n<NB;n++){
      float tx1=s_tr[n][0], ty1=s_tr[n][1], tx2=s_tr[n][2], ty2=s_tr[n][3];
      float lx=fmaxf(tx1,bx1), ly=fmaxf(ty1,by1);
      float rx=fminf(tx2,bx2), ry=fminf(ty2,by2);
      float w=fmaxf(rx-lx,0.f), h=fmaxf(ry-ly,0.f);
      float inter=w*h;
      float area_a=(tx2-tx1)*(ty2-ty1);
      float iou = inter/(area_a+area_b-inter);
      if (iou > bestov){ bestov=iou; bestn=n; }          // strict > = first-max over n
      unsigned long long key = ((unsigned long long)__float_as_uint(iou)<<32)
                             | (unsigned long long)(0xFFFFFFFFu - (unsigned)p);
      if (key > bk[n]) bk[n] = key;                      // max iou, tie -> min p
    }
    rank[(long)b*PP + p] = bestov;
    idxa[(long)b*PP + p] = (unsigned char)bestn;
  }

  #pragma unroll
  for (int n=0;n<NB;n++){
    unsigned long long k2 = bk[n];
    #pragma unroll
    for (int o=32;o;o>>=1){ unsigned long long w=__shfl_down(k2,o,64); if (w>k2) k2=w; }
    if (lane==0 && k2) atomicMax(&keys[b*NB+n], k2);
  }
}

// ---- B: scatter overrides, ascending n. 1 block, one thread per row ----
extern "C" __global__ void mb_scatter(float* __restrict__ rank,
                                      unsigned char* __restrict__ idxa,
                                      const unsigned long long* __restrict__ keys,
                                      int B)
{
  int b = threadIdx.x;
  if (b >= B) return;
  unsigned long long k[NB];
  #pragma unroll
  for (int n=0;n<NB;n++) k[n] = keys[b*NB+n];
  #pragma unroll
  for (int n=0;n<NB;n++){
    int p = (int)(0xFFFFFFFFu - (unsigned)(k[n] & 0xFFFFFFFFULL));
    rank[(long)b*PP + p] = 2.0f;
    idxa[(long)b*PP + p] = (unsigned char)n;   // ascending overwrite => max n wins
  }
}

// ---- C: conf_t, logsumexp, positive losses, rank values. grid (B, SC) ----
extern "C" __global__ void __launch_bounds__(BTH)
mb_rank(const float* __restrict__ loc_data, const float* __restrict__ conf_data,
        const float* __restrict__ priors, const float* __restrict__ targets,
        float* __restrict__ rank, const unsigned char* __restrict__ idxa,
        float* __restrict__ facc, int* __restrict__ iacc, int* __restrict__ nposa)
{
  const int b = blockIdx.x, tid = threadIdx.x, lane = tid & 63, wid = tid >> 6;
  __shared__ float s_tr[NB][4];
  __shared__ float s_lab[NB];
  __shared__ float s_red[2*NW];
  __shared__ int   s_redi[NW];
  if (tid < NB*5){
    int n = tid/5, k2 = tid - n*5;
    float v = targets[((long)b*NB + n)*5 + k2];
    if (k2 < 4) s_tr[n][k2] = v; else s_lab[n] = v;
  }
  __syncthreads();

  float loss_l=0.f, posce=0.f; int np=0;
  const int base = blockIdx.y*CHC;
  const int end  = (base + CHC < PP) ? base + CHC : PP;
  for (int p = base + tid; p < end; p += BTH){
    const long gp = (long)b*PP + p;
    float ov = rank[gp];
    int idx = idxa[gp];
    int ct = (ov < 0.5f) ? 0 : ((int)s_lab[idx] + 1);
    const float* cp = conf_data + gp*NC;
    float v[NC];
    #pragma unroll
    for (int c=0;c<NC;c++) v[c]=cp[c];
    float m=v[0];
    #pragma unroll
    for (int c=1;c<NC;c++) m=fmaxf(m,v[c]);
    float s=0.f;
    #pragma unroll
    for (int c=0;c<NC;c++) s += expf(v[c]-m);
    float lse = logf(s)+m;
    float rv;
    if (ct > 0){
      float vct = v[0];
      #pragma unroll
      for (int c=1;c<NC;c++) if (ct==c) vct=v[c];
      posce += lse - vct;
      np++;
      float tx1=s_tr[idx][0], ty1=s_tr[idx][1], tx2=s_tr[idx][2], ty2=s_tr[idx][3];
      float4 pr = reinterpret_cast<const float4*>(priors)[p];
      float g0 = ((tx1+tx2)*0.5f - pr.x) / (0.1f*pr.z);
      float g1 = ((ty1+ty2)*0.5f - pr.y) / (0.1f*pr.w);
      float g2 = logf((tx2-tx1)/pr.z) / 0.2f;
      float g3 = logf((ty2-ty1)/pr.w) / 0.2f;
      float4 ld = reinterpret_cast<const float4*>(loc_data)[gp];
      loss_l += sl1(ld.x-g0)+sl1(ld.y-g1)+sl1(ld.z-g2)+sl1(ld.w-g3);
      rv = 0.f;
    } else {
      // clamped class: 0, except flat index 0 which is forced to class 1
      if (b==0 && p==0){
        rv = lse - v[1];
        facc[2] = lse - v[0];   // true ce if flat index 0 gets selected as negative
        iacc[0] = 1;
      } else {
        rv = lse - v[0];
      }
    }
    rank[gp] = rv;
  }

  #pragma unroll
  for (int o=32;o;o>>=1){
    loss_l += __shfl_down(loss_l,o,64);
    posce  += __shfl_down(posce,o,64);
    np     += __shfl_down(np,o,64);
  }
  if (lane==0){ s_red[wid]=loss_l; s_red[NW+wid]=posce; s_redi[wid]=np; }
  __syncthreads();
  if (tid==0){
    float a=0.f,c2=0.f; int ni=0;
    for (int w=0;w<NW;w++){ a+=s_red[w]; c2+=s_red[NW+w]; ni+=s_redi[w]; }
    if (a  != 0.f) atomicAdd(&facc[0], a);
    if (c2 != 0.f) atomicAdd(&facc[1], c2);
    if (ni) atomicAdd(&nposa[b], ni);
  }
}

// ---- D: per-row exact top-k via binary search on float bits. grid (B) ----
extern "C" __global__ void __launch_bounds__(BTH)
mb_select(const float* __restrict__ rank, const int* __restrict__ nposa,
          float* __restrict__ facc, const int* __restrict__ iacc)
{
  const int b = blockIdx.x, tid = threadIdx.x, lane = tid & 63, wid = tid >> 6;
  __shared__ float s_val[PP];
  __shared__ float s_scrf[NW];
  __shared__ int   s_scri[NW];

  // stage row into LDS, coalesced float4 (PP = 2183*4, row base 16B-aligned)
  const float4* rr = reinterpret_cast<const float4*>(rank + (long)b*PP);
  for (int i = tid; i < PP/4; i += BTH)
    reinterpret_cast<float4*>(s_val)[i] = rr[i];
  __syncthreads();

  const int num_pos = nposa[b];
  int k = num_pos*3; if (k > PP-1) k = PP-1;
  if (k <= 0) return;

  unsigned lo=0u, hi=0x7f800000u;
  while (lo < hi){
    unsigned mid = lo + ((hi - lo + 1u) >> 1);
    int c=0;
    for (int p=tid;p<PP;p+=BTH) c += (__float_as_uint(s_val[p]) >= mid) ? 1 : 0;
    #pragma unroll
    for (int o=32;o;o>>=1) c += __shfl_down(c,o,64);
    __syncthreads();
    if (lane==0) s_scri[wid]=c;
    __syncthreads();
    int tot=0;
    for (int w=0;w<NW;w++) tot+=s_scri[w];
    if (tot >= k) lo = mid; else hi = mid - 1u;
  }
  const unsigned vstar = lo;

  int cg=0; float sg=0.f;
  for (int p=tid;p<PP;p+=BTH){
    float rv = s_val[p];
    if (__float_as_uint(rv) > vstar){ cg++; sg += rv; }
  }
  #pragma unroll
  for (int o=32;o;o>>=1){ cg += __shfl_down(cg,o,64); sg += __shfl_down(sg,o,64); }
  __syncthreads();
  if (lane==0){ s_scri[wid]=cg; s_scrf[wid]=sg; }
  __syncthreads();
  if (tid==0){
    int cG=0; float sumG=0.f;
    for (int w=0;w<NW;w++){ cG+=s_scri[w]; sumG+=s_scrf[w]; }
    int tie = k - cG;   // >=1 by construction; stable ties take lowest indices first
    float negsum = sumG;
    if (tie > 0) negsum += (float)tie * __uint_as_float(vstar);
    // flat-index-0 correction: ranked with class 1, true ce uses class 0.
    // index 0 is first among equal ties, so selected iff bits >= vstar.
    if (b==0 && iacc[0]){
      if (__float_as_uint(s_val[0]) >= vstar) negsum += facc[2] - s_val[0];
    }
    atomicAdd(&facc[3], negsum);
  }
}

// ---- E: final reduce, one wave ----
extern "C" __global__ void mb_out(const float* __restrict__ facc,
                                  const int* __restrict__ nposa,
                                  float* __restrict__ out, int B)
{
  int tid = threadIdx.x;
  int np = 0;
  for (int i = tid; i < B; i += 64) np += nposa[i];
  #pragma unroll
  for (int o=32;o;o>>=1) np += __shfl_down(np,o,64);
  if (tid==0){
    float Nf = (float)np;
    out[0] = facc[0] / Nf;
    out[1] = (facc[1] + facc[3]) / Nf;
  }
}

extern "C" void kernel_launch(void* const* d_in, const int* in_sizes, int n_in,
                              void* d_out, int out_size, void* d_ws, size_t ws_size,
                              hipStream_t stream) {
  const float* loc     = (const float*)d_in[0];
  const float* conf    = (const float*)d_in[1];
  const float* priors  = (const float*)d_in[2];
  const float* targets = (const float*)d_in[3];
  float* out = (float*)d_out;
  int B = in_sizes[0] / (PP*4);

  char* ws = (char*)d_ws;
  unsigned long long* keys = (unsigned long long*)ws;
  float* facc = (float*)(ws + OFF_FACC);
  int*   iacc = (int*)(ws + OFF_IACC);
  int*   nposa= (int*)(ws + OFF_NPOS);
  float* rank = (float*)(ws + OFF_RANK);
  unsigned char* idxa = (unsigned char*)(ws + OFF_RANK + (size_t)B*PP*4);

  hipMemsetAsync(d_ws, 0, OFF_RANK, stream);
  hipLaunchKernelGGL(mb_match,  dim3(B, SA), dim3(BTH), 0, stream, priors, targets, rank, idxa, keys);
  hipLaunchKernelGGL(mb_scatter, dim3(1), dim3(BTH), 0, stream, rank, idxa, keys, B);
  hipLaunchKernelGGL(mb_rank,   dim3(B, SC), dim3(BTH), 0, stream,
                     loc, conf, priors, targets, rank, idxa, facc, iacc, nposa);
  hipLaunchKernelGGL(mb_select, dim3(B), dim3(BTH), 0, stream, rank, nposa, facc, iacc);
  hipLaunchKernelGGL(mb_out,    dim3(1), dim3(64), 0, stream, facc, nposa, out, B);
}